// Round 8
// baseline (108.491 us; speedup 1.0000x reference)
//
#include <hip/hip_runtime.h>

#define NB 16
#define SS 2048
#define DD 64

typedef __attribute__((ext_vector_type(8))) short short8;
typedef __attribute__((ext_vector_type(4))) float f32x4;

// SCALE * log2(e), folded so softmax exp is one v_mul + one v_exp
#define SCL2E 0.18033688011112042f

// async global->LDS, 16B per lane (LDS dest = wave-uniform base + lane*16)
#define GLOAD_LDS(g, l) __builtin_amdgcn_global_load_lds( \
    (const __attribute__((address_space(1))) void*)(g),   \
    (__attribute__((address_space(3))) void*)(l), 16, 0, 0)

// counted vmcnt wait (literal N) with compiler memory fence (T4)
#define WAITV(N) asm volatile("s_waitcnt vmcnt(" #N ")" ::: "memory")

// round-to-nearest-even f32 -> bf16 (as raw short)
__device__ __forceinline__ short f2bf(float f) {
  union { float f; unsigned u; } v; v.f = f;
  unsigned r = (v.u + 0x7fffu + ((v.u >> 16) & 1u)) >> 16;
  return (short)r;
}

// packed RNE f32x2 -> bf16x2 (no builtin on gfx950; guide T12)
__device__ __forceinline__ unsigned cvtpk_bf16(float lo, float hi) {
  unsigned r;
  asm("v_cvt_pk_bf16_f32 %0, %1, %2" : "=v"(r) : "v"(lo), "v"(hi));
  return r;
}

__device__ __forceinline__ short8 load_a_frag_f32(const float* p) {
  float4 u = *(const float4*)p;
  float4 w = *(const float4*)(p + 4);
  short8 r;
  r[0] = f2bf(u.x); r[1] = f2bf(u.y); r[2] = f2bf(u.z); r[3] = f2bf(u.w);
  r[4] = f2bf(w.x); r[5] = f2bf(w.y); r[6] = f2bf(w.z); r[7] = f2bf(w.w);
  return r;
}

// ---------------------------------------------------------------------------
// QKV projection (byte-identical to r7, harness-verified): pre-swizzled K and
// V-tile stores (byte_col ^= (row&7)<<4 per 128B row) so attn's linear
// global_load_lds staging lands XOR-swizzled content in LDS.
// ---------------------------------------------------------------------------
__global__ __launch_bounds__(768) void proj_kernel(
    const float* __restrict__ x,
    const float* __restrict__ Wq, const float* __restrict__ bq,
    const float* __restrict__ Wk, const float* __restrict__ bk,
    const float* __restrict__ Wv, const float* __restrict__ bv,
    ushort* __restrict__ qo, ushort* __restrict__ ko, ushort* __restrict__ vt)
{
  __shared__ __align__(16) ushort Wt[3][64][72];   // W^T[n][k], bf16
  __shared__ __align__(16) ushort Vs[64][68];
  const int t = threadIdx.x;
#pragma unroll
  for (int i = 0; i < 4; ++i) {
    int idx = i * 3072 + t * 4;
    int m = idx >> 12, rem = idx & 4095;
    int kk = rem >> 6, n0 = rem & 63;
    const float* src = (m == 0 ? Wq : (m == 1 ? Wk : Wv));
    float4 w4 = *(const float4*)(src + rem);
    Wt[m][n0 + 0][kk] = (ushort)f2bf(w4.x);
    Wt[m][n0 + 1][kk] = (ushort)f2bf(w4.y);
    Wt[m][n0 + 2][kk] = (ushort)f2bf(w4.z);
    Wt[m][n0 + 3][kk] = (ushort)f2bf(w4.w);
  }
  __syncthreads();

  const int lane = t & 63, w = t >> 6;   // w in 0..11
  const int l15 = lane & 15, quad = lane >> 4;
  const int mm = w >> 2, rr = w & 3;     // matrix, row-quarter
  const int g = blockIdx.x * 64 + rr * 16 + l15;

  short8 b0 = load_a_frag_f32(x + (size_t)g * 64 + quad * 8);
  short8 b1 = load_a_frag_f32(x + (size_t)g * 64 + 32 + quad * 8);

  const float* bp = (mm == 0 ? bq : (mm == 1 ? bk : bv));
  ushort* outp = (mm == 0 ? qo : ko);

#pragma unroll
  for (int nt = 0; nt < 4; ++nt) {
    const ushort* ap = &Wt[mm][nt * 16 + l15][quad * 8];
    short8 a0 = *(const short8*)ap;
    short8 a1 = *(const short8*)(ap + 32);
    f32x4 acc = {0.f, 0.f, 0.f, 0.f};
    acc = __builtin_amdgcn_mfma_f32_16x16x32_bf16(a0, b0, acc, 0, 0, 0);
    acc = __builtin_amdgcn_mfma_f32_16x16x32_bf16(a1, b1, acc, 0, 0, 0);
    float4 bb = *(const float4*)(bp + nt * 16 + quad * 4);
    uint2 pk;
    pk.x = cvtpk_bf16(acc[0] + bb.x, acc[1] + bb.y);
    pk.y = cvtpk_bf16(acc[2] + bb.z, acc[3] + bb.w);
    if (mm == 2) {
      *(uint2*)&Vs[rr * 16 + l15][nt * 16 + quad * 4] = pk;
    } else {
      int colb = (nt * 16 + quad * 4) * 2;          // 8B-aligned byte col
      if (mm == 1) colb ^= (g & 7) << 4;            // K: swizzle within row
      *(uint2*)((char*)outp + (size_t)g * 128 + colb) = pk;
    }
  }
  __syncthreads();
  if (t < 256) {
    const int batch = blockIdx.x >> 5;
    const int ktile = blockIdx.x & 31;
    const int d = t >> 2, j0 = (t & 3) * 16;
    ushort tmp[16];
#pragma unroll
    for (int j = 0; j < 16; ++j) tmp[j] = Vs[j0 + j][d];
    // vtile[b][ktile][d][64 keys], swizzled by d-row
    char* base = (char*)vt + ((size_t)batch * SS * DD + ktile * 4096) * 2 + d * 128;
    const int sw = (d & 7) << 4;
    *(int4*)(base + ((j0 * 2) ^ sw)) = ((int4*)tmp)[0];        // keys j0..j0+7
    *(int4*)(base + ((j0 * 2 + 16) ^ sw)) = ((int4*)tmp)[1];   // keys j0+8..+15
  }
}

// ---------------------------------------------------------------------------
// In-register P redistribution (harness-verified r1-r7).
// ---------------------------------------------------------------------------
__device__ __forceinline__ short8 build_pa(unsigned A0, unsigned A1,
                                           unsigned B0, unsigned B1, int quad) {
  int xA0 = __shfl_xor((int)A0, 32);
  int xA1 = __shfl_xor((int)A1, 32);
  int xB0 = __shfl_xor((int)B0, 32);
  int xB1 = __shfl_xor((int)B1, 32);
  const bool hi = quad >= 2;
  const bool odd = quad & 1;
  int Lo0 = hi ? xB0 : (int)A0;   // [A_lo | B_lo]
  int Lo1 = hi ? xB1 : (int)A1;
  int Hi0 = hi ? (int)B0 : xA0;   // [A_hi | B_hi]
  int Hi1 = hi ? (int)B1 : xA1;
  int xLo0 = __shfl_xor(Lo0, 16);
  int xLo1 = __shfl_xor(Lo1, 16);
  int xHi0 = __shfl_xor(Hi0, 16);
  int xHi1 = __shfl_xor(Hi1, 16);
  int4 wv;
  wv.x = odd ? xHi0 : Lo0;   // keys quad*8 + 0,1
  wv.y = odd ? xHi1 : Lo1;   // keys quad*8 + 2,3
  wv.z = odd ? Hi0 : xLo0;   // keys quad*8 + 4,5
  wv.w = odd ? Hi1 : xLo1;   // keys quad*8 + 6,7
  return *(short8*)&wv;
}

// exp + in-register P build + PV for 16 queries x 32 keys (one key-half).
template<bool MASKED>
__device__ __forceinline__ void attn32(
    const f32x4 (&c)[2], float& l_acc, f32x4 (&acc)[4],
    const short8 (&vf)[4], int keybase, int qabs, int quad)
{
  unsigned pk[2][2];
#pragma unroll
  for (int c2 = 0; c2 < 2; ++c2) {
    float pe[4];
#pragma unroll
    for (int r = 0; r < 4; ++r) {
      float p = __builtin_amdgcn_exp2f(c[c2][r] * SCL2E);
      if (MASKED && (keybase + c2 * 16 + quad * 4 + r > qabs)) p = 0.f;
      pe[r] = p;
      l_acc += p;
    }
    pk[c2][0] = cvtpk_bf16(pe[0], pe[1]);
    pk[c2][1] = cvtpk_bf16(pe[2], pe[3]);
  }
  short8 pa = build_pa(pk[0][0], pk[0][1], pk[1][0], pk[1][1], quad);
  __builtin_amdgcn_s_setprio(1);
#pragma unroll
  for (int nt = 0; nt < 4; ++nt)
    acc[nt] = __builtin_amdgcn_mfma_f32_16x16x32_bf16(pa, vf[nt], acc[nt], 0, 0, 0);
  __builtin_amdgcn_s_setprio(0);
}

// cooperative stage of one 16KB K+V tile: 8 waves x 2KB, 2 gload_lds each
__device__ __forceinline__ void stage_tile(
    char* lds, const ushort* kg, const ushort* vt,
    size_t bbyte, int kt, int seg, int lane)
{
  const char* src = (seg < 4)
      ? (const char*)kg + bbyte + (size_t)kt * 8192 + seg * 2048
      : (const char*)vt + bbyte + (size_t)kt * 8192 + (seg - 4) * 2048;
  char* dst = lds + seg * 2048;   // K at 0..8191, V at 8192..16383
  GLOAD_LDS(src + lane * 16, dst);
  GLOAD_LDS(src + 1024 + lane * 16, dst + 1024);
}

// ---------------------------------------------------------------------------
// Flash causal attention v10: 3-buffer COUNTED-vmcnt pipeline (T4).
// Per tile: stage(kt+2) -> ds_read+compute(kt) -> s_waitcnt vmcnt(2)
// (tile kt+1 landed; kt+2 stays in flight) -> ONE s_barrier -> rotate.
// vs r7's drain-0 syncthreads: stage latency now hides under ~2 compute
// windows instead of <1. Buffer-overwrite safety: readers of bufC's old
// tile finished before the barrier that ended iteration kt-1 (one barrier
// ahead of this stage) -- single barrier per tile is sufficient.
// ---------------------------------------------------------------------------
__global__ __launch_bounds__(512) void attn_kernel(
    const ushort* __restrict__ qg, const ushort* __restrict__ kg,
    const ushort* __restrict__ vt, float* __restrict__ out)
{
  __shared__ __align__(16) char KV[3][16384];   // per buf: K 8KB | V 8KB

  const int t = threadIdx.x, bid = blockIdx.x;
  const int batch = (bid & 7) * 2 + ((bid >> 3) & 1);  // 2 batches per XCD
  const int qt = 31 - (bid >> 4);                      // 64q tile, heavy first
  const int lane = t & 63, w = t >> 6;                 // 8 waves
  const int l15 = lane & 15, quad = lane >> 4;
  const int h = w >> 2;                                // key half (0/1)
  const int qgi = w & 3;                               // query subtile
  const int qrow0 = qt * 64 + qgi * 16;
  const size_t bbase = (size_t)batch * SS * DD;        // elements
  const size_t bbyte = bbase * 2;                      // bytes

  // Q fragments (B operand of swapped QK): lane l15 = query row
  const ushort* qp = qg + bbase + (size_t)(qrow0 + l15) * 64 + quad * 8;
  short8 a0 = *(const short8*)qp;
  short8 a1 = *(const short8*)(qp + 32);

  f32x4 acc[4];
  float l = 0.f;
#pragma unroll
  for (int nt = 0; nt < 4; ++nt) acc[nt] = (f32x4){0.f, 0.f, 0.f, 0.f};

  const int ktotal = qt + 1;
  const int qabs = qrow0 + l15;

  // rotating buffer pointers (register, no runtime-indexed arrays)
  char* bufA = &KV[0][0];   // compute tile kt
  char* bufB = &KV[1][0];   // tile kt+1 (landed by barrier)
  char* bufC = &KV[2][0];   // tile kt+2 (in flight)

  // prologue: stage tiles 0 and 1; publish tile 0
  stage_tile(bufA, kg, vt, bbyte, 0, w, lane);
  if (ktotal > 1) {
    stage_tile(bufB, kg, vt, bbyte, 1, w, lane);
    WAITV(2);
  } else {
    WAITV(0);
  }
  __builtin_amdgcn_s_barrier();

  for (int kt = 0; kt < ktotal; ++kt) {
    if (kt + 2 < ktotal)
      stage_tile(bufC, kg, vt, bbyte, kt + 2, w, lane);

    const char* Kb = bufA;
    const char* Vb = bufA + 8192;
    short8 kf0[2], kf1[2], vf[4];
#pragma unroll
    for (int c2 = 0; c2 < 2; ++c2) {
      int row = (2 * h + c2) * 16 + l15;      // key row in tile
      int sw = (row & 7) << 4;
      kf0[c2] = *(const short8*)(Kb + row * 128 + ((quad * 16) ^ sw));
      kf1[c2] = *(const short8*)(Kb + row * 128 + ((64 + quad * 16) ^ sw));
    }
#pragma unroll
    for (int nt = 0; nt < 4; ++nt) {
      int drow = nt * 16 + l15;               // d row in V tile
      int sv = (drow & 7) << 4;
      vf[nt] = *(const short8*)(Vb + drow * 128 + ((h * 64 + quad * 16) ^ sv));
    }

    // Swapped QK: c = mfma(K, Q) -> S^T; lane l15 = query.
    f32x4 c[2];
    __builtin_amdgcn_s_setprio(1);
#pragma unroll
    for (int c2 = 0; c2 < 2; ++c2) {
      f32x4 z = {0.f, 0.f, 0.f, 0.f};
      c[c2] = __builtin_amdgcn_mfma_f32_16x16x32_bf16(kf0[c2], a0, z, 0, 0, 0);
      c[c2] = __builtin_amdgcn_mfma_f32_16x16x32_bf16(kf1[c2], a1, c[c2], 0, 0, 0);
    }
    __builtin_amdgcn_s_setprio(0);

    const int keybase = kt * 64 + h * 32;
    if (kt == ktotal - 1)
      attn32<true >(c, l, acc, vf, keybase, qabs, quad);
    else
      attn32<false>(c, l, acc, vf, keybase, qabs, quad);

    if (kt + 1 < ktotal) {
      if (kt + 2 < ktotal) { WAITV(2); }   // tile kt+1 landed, kt+2 in flight
      else                 { WAITV(0); }   // nothing beyond kt+1
      __builtin_amdgcn_s_barrier();
    }
    // rotate: A<-B (next compute), B<-C (in flight), C<-A (free)
    char* tmp = bufA; bufA = bufB; bufB = bufC; bufC = tmp;
  }

  // l per-lane (q = l15); fold the 4 quads (each held different keys)
  l += __shfl_xor(l, 16);
  l += __shfl_xor(l, 32);

  __syncthreads();   // all waves done with staging buffers before reuse

  // 2-way combine of key-halves through the (now free) staging LDS
  float* S = (float*)&KV[qgi >> 1][(qgi & 1) * 8192];
  if (h == 1) {
#pragma unroll
    for (int r = 0; r < 4; ++r)
#pragma unroll
      for (int nt = 0; nt < 4; ++nt)
        S[(quad * 4 + r) * 68 + nt * 16 + l15] = acc[nt][r];
    if (lane < 16) S[1088 + lane] = l;
  }
  __syncthreads();
  if (h == 0) {
    float lt = l + S[1088 + l15];   // total denom for q = l15
#pragma unroll
    for (int r = 0; r < 4; ++r) {
      float iv = 1.0f / __shfl(lt, quad * 4 + r);
      float* orow = out + bbase + (size_t)(qrow0 + quad * 4 + r) * 64 + l15;
#pragma unroll
      for (int nt = 0; nt < 4; ++nt)
        orow[nt * 16] = (acc[nt][r] + S[(quad * 4 + r) * 68 + nt * 16 + l15]) * iv;
    }
  }
}

extern "C" void kernel_launch(void* const* d_in, const int* in_sizes, int n_in,
                              void* d_out, int out_size, void* d_ws, size_t ws_size,
                              hipStream_t stream) {
  (void)in_sizes; (void)n_in; (void)out_size; (void)ws_size;
  const float* x  = (const float*)d_in[0];
  const float* Wq = (const float*)d_in[1];
  const float* bq = (const float*)d_in[2];
  const float* Wk = (const float*)d_in[3];
  const float* bk = (const float*)d_in[4];
  const float* Wv = (const float*)d_in[5];
  const float* bv = (const float*)d_in[6];
  float* out = (float*)d_out;

  ushort* qws = (ushort*)d_ws;                       // bf16 q: 4 MB
  ushort* kws = qws + (size_t)NB * SS * DD;          // bf16 k (swizzled): 4 MB
  ushort* vws = kws + (size_t)NB * SS * DD;          // bf16 vtile (swizzled): 4 MB

  proj_kernel<<<dim3(NB * SS / 64), dim3(768), 0, stream>>>(
      x, Wq, bq, Wk, bk, Wv, bv, qws, kws, vws);
  attn_kernel<<<dim3(NB * (SS / 64)), dim3(512), 0, stream>>>(
      qws, kws, vws, out);
}

// Round 9
// 98.866 us; speedup vs baseline: 1.0974x; 1.0974x over previous
//
#include <hip/hip_runtime.h>

#define NB 16
#define SS 2048
#define DD 64

typedef __attribute__((ext_vector_type(8))) short short8;
typedef __attribute__((ext_vector_type(4))) float f32x4;

// SCALE * log2(e), folded so softmax exp is one v_mul + one v_exp
#define SCL2E 0.18033688011112042f

// async global->LDS, 16B per lane (LDS dest = wave-uniform base + lane*16)
#define GLOAD_LDS(g, l) __builtin_amdgcn_global_load_lds( \
    (const __attribute__((address_space(1))) void*)(g),   \
    (__attribute__((address_space(3))) void*)(l), 16, 0, 0)

// round-to-nearest-even f32 -> bf16 (as raw short)
__device__ __forceinline__ short f2bf(float f) {
  union { float f; unsigned u; } v; v.f = f;
  unsigned r = (v.u + 0x7fffu + ((v.u >> 16) & 1u)) >> 16;
  return (short)r;
}

// packed RNE f32x2 -> bf16x2 (no builtin on gfx950; guide T12)
__device__ __forceinline__ unsigned cvtpk_bf16(float lo, float hi) {
  unsigned r;
  asm("v_cvt_pk_bf16_f32 %0, %1, %2" : "=v"(r) : "v"(lo), "v"(hi));
  return r;
}

__device__ __forceinline__ short8 load_a_frag_f32(const float* p) {
  float4 u = *(const float4*)p;
  float4 w = *(const float4*)(p + 4);
  short8 r;
  r[0] = f2bf(u.x); r[1] = f2bf(u.y); r[2] = f2bf(u.z); r[3] = f2bf(u.w);
  r[4] = f2bf(w.x); r[5] = f2bf(w.y); r[6] = f2bf(w.z); r[7] = f2bf(w.w);
  return r;
}

// ---------------------------------------------------------------------------
// QKV projection (r7 structure) with PV-PERMUTED V columns:
// within each 32-key half, key s32 = ct*16+quad*4+r is stored at column
// quad*8 + ct*4 + r. This makes the swapped-QK lane-held P values ALREADY
// match the PV A-operand slots -> attn needs ZERO cross-lane shuffles.
// K/Q stores unchanged (K swizzled by row as before).
// ---------------------------------------------------------------------------
__global__ __launch_bounds__(768) void proj_kernel(
    const float* __restrict__ x,
    const float* __restrict__ Wq, const float* __restrict__ bq,
    const float* __restrict__ Wk, const float* __restrict__ bk,
    const float* __restrict__ Wv, const float* __restrict__ bv,
    ushort* __restrict__ qo, ushort* __restrict__ ko, ushort* __restrict__ vt)
{
  __shared__ __align__(16) ushort Wt[3][64][72];   // W^T[n][k], bf16
  __shared__ __align__(16) ushort Vs[64][68];
  const int t = threadIdx.x;
#pragma unroll
  for (int i = 0; i < 4; ++i) {
    int idx = i * 3072 + t * 4;
    int m = idx >> 12, rem = idx & 4095;
    int kk = rem >> 6, n0 = rem & 63;
    const float* src = (m == 0 ? Wq : (m == 1 ? Wk : Wv));
    float4 w4 = *(const float4*)(src + rem);
    Wt[m][n0 + 0][kk] = (ushort)f2bf(w4.x);
    Wt[m][n0 + 1][kk] = (ushort)f2bf(w4.y);
    Wt[m][n0 + 2][kk] = (ushort)f2bf(w4.z);
    Wt[m][n0 + 3][kk] = (ushort)f2bf(w4.w);
  }
  __syncthreads();

  const int lane = t & 63, w = t >> 6;   // w in 0..11
  const int l15 = lane & 15, quad = lane >> 4;
  const int mm = w >> 2, rr = w & 3;     // matrix, row-quarter
  const int g = blockIdx.x * 64 + rr * 16 + l15;

  short8 b0 = load_a_frag_f32(x + (size_t)g * 64 + quad * 8);
  short8 b1 = load_a_frag_f32(x + (size_t)g * 64 + 32 + quad * 8);

  const float* bp = (mm == 0 ? bq : (mm == 1 ? bk : bv));
  ushort* outp = (mm == 0 ? qo : ko);

#pragma unroll
  for (int nt = 0; nt < 4; ++nt) {
    const ushort* ap = &Wt[mm][nt * 16 + l15][quad * 8];
    short8 a0 = *(const short8*)ap;
    short8 a1 = *(const short8*)(ap + 32);
    f32x4 acc = {0.f, 0.f, 0.f, 0.f};
    acc = __builtin_amdgcn_mfma_f32_16x16x32_bf16(a0, b0, acc, 0, 0, 0);
    acc = __builtin_amdgcn_mfma_f32_16x16x32_bf16(a1, b1, acc, 0, 0, 0);
    float4 bb = *(const float4*)(bp + nt * 16 + quad * 4);
    uint2 pk;
    pk.x = cvtpk_bf16(acc[0] + bb.x, acc[1] + bb.y);
    pk.y = cvtpk_bf16(acc[2] + bb.z, acc[3] + bb.w);
    if (mm == 2) {
      *(uint2*)&Vs[rr * 16 + l15][nt * 16 + quad * 4] = pk;
    } else {
      int colb = (nt * 16 + quad * 4) * 2;          // 8B-aligned byte col
      if (mm == 1) colb ^= (g & 7) << 4;            // K: swizzle within row
      *(uint2*)((char*)outp + (size_t)g * 128 + colb) = pk;
    }
  }
  __syncthreads();
  if (t < 256) {
    const int batch = blockIdx.x >> 5;
    const int ktile = blockIdx.x & 31;
    const int d = t >> 2, j0 = (t & 3) * 16;
    ushort tmp[16];
#pragma unroll
    for (int j = 0; j < 16; ++j) tmp[j] = Vs[j0 + j][d];
    // vtile[b][ktile][d][64 keys], row-swizzled AND column-permuted:
    // key s (within 32-key half) -> column quad(s)*8 + ct(s)*4 + r(s).
    // This thread's 16 keys are one (half, ct) group -> 4 chunks of 4 keys
    // at byte columns bcol + jj*16.
    char* base = (char*)vt + ((size_t)batch * SS * DD + ktile * 4096) * 2 + d * 128;
    const int sw = (d & 7) << 4;
    const int bcol = ((j0 >> 5) << 6) + (((j0 >> 4) & 1) << 3);
#pragma unroll
    for (int jj = 0; jj < 4; ++jj)
      *(uint2*)(base + ((bcol + jj * 16) ^ sw)) = ((uint2*)tmp)[jj];
  }
}

// ---------------------------------------------------------------------------
// exp + SHUFFLE-FREE in-lane P repack + PV for 16 queries x 32 keys.
// Swapped QK gives lane(l15=q, quad): c[ct][r] = S[key kb+ct*16+quad*4+r][q].
// V columns are pre-permuted (proj) so PV A-slot (quad, e=ct*4+r) wants
// exactly this lane's pe[ct][r] -> pa = 4 packed cvtpk words, no ds_bpermute
// (r7's build_pa was 2 chained bpermute rounds ~300-400cy on the critical
// path of every tile).
// ---------------------------------------------------------------------------
template<bool MASKED>
__device__ __forceinline__ void attn32(
    const f32x4 (&c)[2], float& l_acc, f32x4 (&acc)[4],
    const short8 (&vf)[4], int keybase, int qabs, int quad)
{
  unsigned pk[4];
#pragma unroll
  for (int ct = 0; ct < 2; ++ct) {
    float pe[4];
#pragma unroll
    for (int r = 0; r < 4; ++r) {
      float p = __builtin_amdgcn_exp2f(c[ct][r] * SCL2E);
      if (MASKED && (keybase + ct * 16 + quad * 4 + r > qabs)) p = 0.f;
      pe[r] = p;
      l_acc += p;
    }
    pk[ct * 2 + 0] = cvtpk_bf16(pe[0], pe[1]);
    pk[ct * 2 + 1] = cvtpk_bf16(pe[2], pe[3]);
  }
  int4 w4;
  w4.x = (int)pk[0]; w4.y = (int)pk[1]; w4.z = (int)pk[2]; w4.w = (int)pk[3];
  short8 pa = *(short8*)&w4;
  __builtin_amdgcn_s_setprio(1);
#pragma unroll
  for (int nt = 0; nt < 4; ++nt)
    acc[nt] = __builtin_amdgcn_mfma_f32_16x16x32_bf16(pa, vf[nt], acc[nt], 0, 0, 0);
  __builtin_amdgcn_s_setprio(0);
}

// cooperative stage of one 16KB K+V tile: 8 waves x 2KB, 2 gload_lds each
__device__ __forceinline__ void stage_tile(
    char* lds, const ushort* kg, const ushort* vt,
    size_t bbyte, int kt, int seg, int lane)
{
  const char* src = (seg < 4)
      ? (const char*)kg + bbyte + (size_t)kt * 8192 + seg * 2048
      : (const char*)vt + bbyte + (size_t)kt * 8192 + (seg - 4) * 2048;
  char* dst = lds + seg * 2048;   // K at 0..8191, V at 8192..16383
  GLOAD_LDS(src + lane * 16, dst);
  GLOAD_LDS(src + 1024 + lane * 16, dst + 1024);
}

// ---------------------------------------------------------------------------
// Flash causal attention (r7 schedule verbatim: 2-buffer LDS staging,
// per-tile syncthreads) + shuffle-free softmax->PV handoff.
// ---------------------------------------------------------------------------
__global__ __launch_bounds__(512) void attn_kernel(
    const ushort* __restrict__ qg, const ushort* __restrict__ kg,
    const ushort* __restrict__ vt, float* __restrict__ out)
{
  __shared__ __align__(16) char KV[2][16384];   // per buf: K 8KB | V 8KB

  const int t = threadIdx.x, bid = blockIdx.x;
  const int batch = (bid & 7) * 2 + ((bid >> 3) & 1);  // 2 batches per XCD
  const int qt = 31 - (bid >> 4);                      // 64q tile, heavy first
  const int lane = t & 63, w = t >> 6;                 // 8 waves
  const int l15 = lane & 15, quad = lane >> 4;
  const int h = w >> 2;                                // key half (0/1)
  const int qgi = w & 3;                               // query subtile
  const int qrow0 = qt * 64 + qgi * 16;
  const size_t bbase = (size_t)batch * SS * DD;        // elements
  const size_t bbyte = bbase * 2;                      // bytes

  // Q fragments (B operand of swapped QK): lane l15 = query row
  const ushort* qp = qg + bbase + (size_t)(qrow0 + l15) * 64 + quad * 8;
  short8 a0 = *(const short8*)qp;
  short8 a1 = *(const short8*)(qp + 32);

  f32x4 acc[4];
  float l = 0.f;
#pragma unroll
  for (int nt = 0; nt < 4; ++nt) acc[nt] = (f32x4){0.f, 0.f, 0.f, 0.f};

  const int ktotal = qt + 1;
  const int qabs = qrow0 + l15;

  stage_tile(&KV[0][0], kg, vt, bbyte, 0, w, lane);
  __syncthreads();   // drains vmcnt(0): buf0 ready

  int cur = 0;
  for (int kt = 0; kt < ktotal; ++kt) {
    if (kt + 1 < ktotal)
      stage_tile(&KV[cur ^ 1][0], kg, vt, bbyte, kt + 1, w, lane);

    const char* Kb = &KV[cur][0];
    const char* Vb = &KV[cur][8192];
    short8 kf0[2], kf1[2], vf[4];
#pragma unroll
    for (int c2 = 0; c2 < 2; ++c2) {
      int row = (2 * h + c2) * 16 + l15;      // key row in tile
      int sw = (row & 7) << 4;
      kf0[c2] = *(const short8*)(Kb + row * 128 + ((quad * 16) ^ sw));
      kf1[c2] = *(const short8*)(Kb + row * 128 + ((64 + quad * 16) ^ sw));
    }
#pragma unroll
    for (int nt = 0; nt < 4; ++nt) {
      int drow = nt * 16 + l15;               // d row in V tile
      int sv = (drow & 7) << 4;
      vf[nt] = *(const short8*)(Vb + drow * 128 + ((h * 64 + quad * 16) ^ sv));
    }

    // Swapped QK: c = mfma(K, Q) -> S^T; lane l15 = query.
    f32x4 c[2];
    __builtin_amdgcn_s_setprio(1);
#pragma unroll
    for (int c2 = 0; c2 < 2; ++c2) {
      f32x4 z = {0.f, 0.f, 0.f, 0.f};
      c[c2] = __builtin_amdgcn_mfma_f32_16x16x32_bf16(kf0[c2], a0, z, 0, 0, 0);
      c[c2] = __builtin_amdgcn_mfma_f32_16x16x32_bf16(kf1[c2], a1, c[c2], 0, 0, 0);
    }
    __builtin_amdgcn_s_setprio(0);

    const int keybase = kt * 64 + h * 32;
    if (kt == ktotal - 1)
      attn32<true >(c, l, acc, vf, keybase, qabs, quad);
    else
      attn32<false>(c, l, acc, vf, keybase, qabs, quad);

    __syncthreads();   // vmcnt(0) drain of stage + barrier
    cur ^= 1;
  }

  // l per-lane (q = l15); fold the 4 quads (each held different keys)
  l += __shfl_xor(l, 16);
  l += __shfl_xor(l, 32);

  __syncthreads();   // all waves done with staging buffers before reuse

  // 2-way combine of key-halves through the (now free) staging LDS
  float* S = (float*)&KV[qgi >> 1][(qgi & 1) * 8192];
  if (h == 1) {
#pragma unroll
    for (int r = 0; r < 4; ++r)
#pragma unroll
      for (int nt = 0; nt < 4; ++nt)
        S[(quad * 4 + r) * 68 + nt * 16 + l15] = acc[nt][r];
    if (lane < 16) S[1088 + lane] = l;
  }
  __syncthreads();
  if (h == 0) {
    float lt = l + S[1088 + l15];   // total denom for q = l15
#pragma unroll
    for (int r = 0; r < 4; ++r) {
      float iv = 1.0f / __shfl(lt, quad * 4 + r);
      float* orow = out + bbase + (size_t)(qrow0 + quad * 4 + r) * 64 + l15;
#pragma unroll
      for (int nt = 0; nt < 4; ++nt)
        orow[nt * 16] = (acc[nt][r] + S[(quad * 4 + r) * 68 + nt * 16 + l15]) * iv;
    }
  }
}

extern "C" void kernel_launch(void* const* d_in, const int* in_sizes, int n_in,
                              void* d_out, int out_size, void* d_ws, size_t ws_size,
                              hipStream_t stream) {
  (void)in_sizes; (void)n_in; (void)out_size; (void)ws_size;
  const float* x  = (const float*)d_in[0];
  const float* Wq = (const float*)d_in[1];
  const float* bq = (const float*)d_in[2];
  const float* Wk = (const float*)d_in[3];
  const float* bk = (const float*)d_in[4];
  const float* Wv = (const float*)d_in[5];
  const float* bv = (const float*)d_in[6];
  float* out = (float*)d_out;

  ushort* qws = (ushort*)d_ws;                       // bf16 q: 4 MB
  ushort* kws = qws + (size_t)NB * SS * DD;          // bf16 k (swizzled): 4 MB
  ushort* vws = kws + (size_t)NB * SS * DD;          // bf16 vtile (swz+perm): 4 MB

  proj_kernel<<<dim3(NB * SS / 64), dim3(768), 0, stream>>>(
      x, Wq, bq, Wk, bk, Wv, bv, qws, kws, vws);
  attn_kernel<<<dim3(NB * (SS / 64)), dim3(512), 0, stream>>>(
      qws, kws, vws, out);
}